// Round 3
// baseline (157.099 us; speedup 1.0000x reference)
//
#include <hip/hip_runtime.h>

#define N 224        // image size
#define M 32         // CUT (number of sine modes)
#define NPIX (N * N) // 50176 = 196 * 256
#define NCHUNK 196   // 256-pixel chunks per plane
#define NPLANE 384   // 128 * 3
#define P 8          // planes per thread (table amortization + MLP)
#define NPGRP (NPLANE / P)  // 48 plane-groups
#define NXCD 8
#define PI_F 3.14159265358979323846f

// Stage 1: compute both scalar fields, displacement, and the per-pixel
// bilinear gather table (corner offsets + fractional weights).
// One block per row y, one thread per column x.
__global__ __launch_bounds__(256) void field_kernel(
    const float* __restrict__ Fx, const float* __restrict__ Fy,
    int4* __restrict__ offs, float2* __restrict__ wgt)
{
    __shared__ float cx[M][M];
    __shared__ float cy[M][M];
    __shared__ float sy[M];

    const int t = threadIdx.x;
    const int y = blockIdx.x;

    // c = F * e, where e[i][j] = (r < M+0.5) / r, r = sqrt((i+1)^2+(j+1)^2)
    for (int idx = t; idx < M * M; idx += 256) {
        const int i = idx / M, j = idx % M;
        const float fi = (float)(i + 1), fj = (float)(j + 1);
        const float r = sqrtf(fi * fi + fj * fj);
        const float e = (r < (float)M + 0.5f) ? (1.0f / r) : 0.0f;
        cx[i][j] = Fx[idx] * e;
        cy[i][j] = Fy[idx] * e;
    }
    if (t < M) {
        const float ys = (float)y / (float)(N - 1);
        sy[t] = sinf(PI_F * ys * (float)(t + 1));
    }
    __syncthreads();

    if (t >= N) return;  // no further barriers below
    const int x = t;

    // per-thread x-basis: s[x][i] = sin(pi * xs[x] * (i+1))
    float sx[M];
    const float xsv = (float)x / (float)(N - 1);
#pragma unroll
    for (int i = 0; i < M; ++i)
        sx[i] = sinf(PI_F * xsv * (float)(i + 1));

    // field[y][x] = sum_j s[y][j] * (sum_i c[i][j] * s[x][i])
    float u = 0.0f, v = 0.0f;
#pragma unroll 1
    for (int j = 0; j < M; ++j) {
        float tx = 0.0f, ty = 0.0f;
#pragma unroll
        for (int i = 0; i < M; ++i) {
            tx = fmaf(cx[i][j], sx[i], tx);
            ty = fmaf(cy[i][j], sx[i], ty);
        }
        const float syj = sy[j];
        u = fmaf(syj, tx, u);
        v = fmaf(syj, ty, v);
    }

    // dx = sqrt(T)*u*n = 0.1 * 224 * u
    const float dxv = 22.4f * u;
    const float dyv = 22.4f * v;
    const float xn = fminf(fmaxf((float)x + dxv, 0.0f), (float)(N - 1));
    const float yn = fminf(fmaxf((float)y + dyv, 0.0f), (float)(N - 1));
    const float xff = floorf(xn), yff = floorf(yn);
    const int xf = (int)xff, yf = (int)yff;
    const int xc = (int)ceilf(xn), yc = (int)ceilf(yn);

    const int pix = y * N + x;
    offs[pix] = make_int4(yf * N + xf, yf * N + xc, yc * N + xf, yc * N + xc);
    wgt[pix]  = make_float2(xn - xff, yn - yff);
}

// Stage 2: bilinear gather; each thread serves ONE pixel across P=8 planes.
// Table (int4+float2) loaded once per thread, then 8 fully-unrolled
// independent {4 gathers + blend + store} groups -> 32 gathers in flight.
// Grid: NCHUNK * NPGRP blocks, XCD-clustered so all 196 chunks of a
// plane-group land on the SAME XCD (working set 8 planes = 1.6 MB < 4 MB L2):
//   xcd   = bid % 8
//   local = bid / 8                (1176 per XCD)
//   pgrp  = xcd + 8*(local/196)    (6 plane-groups = 48 planes per XCD)
//   chunk = local % 196
__global__ __launch_bounds__(256) void remap_kernel(
    const float* __restrict__ x, const int4* __restrict__ offs,
    const float2* __restrict__ wgt, float* __restrict__ out)
{
    const int bid   = blockIdx.x;
    const int xcd   = bid % NXCD;
    const int local = bid / NXCD;
    const int pgrp  = xcd + NXCD * (local / NCHUNK);
    const int chunk = local % NCHUNK;
    const int pix   = chunk * 256 + threadIdx.x;

    const int4 o = offs[pix];
    const float2 w = wgt[pix];

    const float omx = 1.0f - w.x, omy = 1.0f - w.y;
    const float w00 = omy * omx, w01 = omy * w.x;
    const float w10 = w.y * omx, w11 = w.y * w.x;

    const float* img = x + (size_t)pgrp * P * NPIX;
    float* op = out + (size_t)pgrp * P * NPIX + pix;

#pragma unroll
    for (int p = 0; p < P; ++p) {
        const float* im = img + (size_t)p * NPIX;
        const float v00 = im[o.x];
        const float v01 = im[o.y];
        const float v10 = im[o.z];
        const float v11 = im[o.w];
        op[(size_t)p * NPIX] = w00 * v00 + w01 * v01 + w10 * v10 + w11 * v11;
    }
}

extern "C" void kernel_launch(void* const* d_in, const int* in_sizes, int n_in,
                              void* d_out, int out_size, void* d_ws, size_t ws_size,
                              hipStream_t stream) {
    const float* x  = (const float*)d_in[0];   // [128,3,224,224]
    const float* Fx = (const float*)d_in[1];   // [32,32]
    const float* Fy = (const float*)d_in[2];   // [32,32]
    float* out = (float*)d_out;

    int4*   offs = (int4*)d_ws;
    float2* wgt  = (float2*)((char*)d_ws + (size_t)NPIX * sizeof(int4));

    field_kernel<<<N, 256, 0, stream>>>(Fx, Fy, offs, wgt);

    remap_kernel<<<NCHUNK * NPGRP, 256, 0, stream>>>(x, offs, wgt, out);
}

// Round 4
// 128.543 us; speedup vs baseline: 1.2221x; 1.2221x over previous
//
#include <hip/hip_runtime.h>

#define N 224        // image size
#define M 32         // CUT (number of sine modes)
#define NPIX (N * N) // 50176 = 196 * 256
#define NCHUNK 196   // 256-pixel chunks per plane
#define NPLANE 384   // 128 * 3
#define P 8          // planes per thread
#define NPGRP (NPLANE / P)  // 48 plane-groups
#define NXCD 8
#define PI_F 3.14159265358979323846f

// Unaligned-safe 8B load: emits global_load_dwordx2 (gfx9+ supports
// unaligned global access); degrades to 2x dword if backend declines.
__device__ __forceinline__ float2 load_f2(const float* p) {
    float2 r;
    __builtin_memcpy(&r, p, sizeof(float2));
    return r;
}

// Stage 1: compute both scalar fields, displacement, and the per-pixel
// bilinear table in canonical form: base = by*N+bx with bx=min(xf,N-2),
// fx = xn-bx (identical to the reference's floor/ceil form in all cases,
// including integer xn and xn==N-1 where the degenerate weight selects the
// right sample). One block per row y, one thread per column x.
__global__ __launch_bounds__(256) void field_kernel(
    const float* __restrict__ Fx, const float* __restrict__ Fy,
    int4* __restrict__ tab)
{
    __shared__ float cx[M][M];
    __shared__ float cy[M][M];
    __shared__ float sy[M];

    const int t = threadIdx.x;
    const int y = blockIdx.x;

    // c = F * e, where e[i][j] = (r < M+0.5) / r, r = sqrt((i+1)^2+(j+1)^2)
    for (int idx = t; idx < M * M; idx += 256) {
        const int i = idx / M, j = idx % M;
        const float fi = (float)(i + 1), fj = (float)(j + 1);
        const float r = sqrtf(fi * fi + fj * fj);
        const float e = (r < (float)M + 0.5f) ? (1.0f / r) : 0.0f;
        cx[i][j] = Fx[idx] * e;
        cy[i][j] = Fy[idx] * e;
    }
    if (t < M) {
        const float ys = (float)y / (float)(N - 1);
        sy[t] = sinf(PI_F * ys * (float)(t + 1));
    }
    __syncthreads();

    if (t >= N) return;  // no further barriers below
    const int x = t;

    float sx[M];
    const float xsv = (float)x / (float)(N - 1);
#pragma unroll
    for (int i = 0; i < M; ++i)
        sx[i] = sinf(PI_F * xsv * (float)(i + 1));

    float u = 0.0f, v = 0.0f;
#pragma unroll 1
    for (int j = 0; j < M; ++j) {
        float tx = 0.0f, ty = 0.0f;
#pragma unroll
        for (int i = 0; i < M; ++i) {
            tx = fmaf(cx[i][j], sx[i], tx);
            ty = fmaf(cy[i][j], sx[i], ty);
        }
        const float syj = sy[j];
        u = fmaf(syj, tx, u);
        v = fmaf(syj, ty, v);
    }

    // dx = sqrt(T)*u*n = 0.1 * 224 * u
    const float dxv = 22.4f * u;
    const float dyv = 22.4f * v;
    const float xn = fminf(fmaxf((float)x + dxv, 0.0f), (float)(N - 1));
    const float yn = fminf(fmaxf((float)y + dyv, 0.0f), (float)(N - 1));
    const int bx = min((int)floorf(xn), N - 2);
    const int by = min((int)floorf(yn), N - 2);
    const float fx = xn - (float)bx;
    const float fy = yn - (float)by;

    tab[y * N + x] = make_int4(by * N + bx,
                               __float_as_int(fx), __float_as_int(fy), 0);
}

// Stage 2: bilinear gather; each thread serves ONE pixel across P=8 planes.
// Per plane: TWO unaligned dwordx2 gathers (row-pair each) instead of four
// dword gathers -> halves the per-lane VMEM address count (the measured
// limiter: ~1 divergent lane-address/cycle/CU). Nontemporal stores keep the
// XCD-resident input planes from being evicted by output write-allocate.
// Grid: NCHUNK * NPGRP blocks, XCD-clustered (all 196 chunks of a
// plane-group on the SAME XCD; working set 8 planes = 1.6 MB < 4 MB L2):
//   xcd = bid % 8; local = bid / 8; pgrp = xcd + 8*(local/196); chunk = local%196
__global__ __launch_bounds__(256) void remap_kernel(
    const float* __restrict__ x, const int4* __restrict__ tab,
    float* __restrict__ out)
{
    const int bid   = blockIdx.x;
    const int xcd   = bid % NXCD;
    const int local = bid / NXCD;
    const int pgrp  = xcd + NXCD * (local / NCHUNK);
    const int chunk = local % NCHUNK;
    const int pix   = chunk * 256 + threadIdx.x;

    const int4 tb = tab[pix];
    const float fx = __int_as_float(tb.y);
    const float fy = __int_as_float(tb.z);

    const float omx = 1.0f - fx, omy = 1.0f - fy;
    const float w00 = omy * omx, w01 = omy * fx;
    const float w10 = fy * omx,  w11 = fy * fx;

    const float* p0 = x + (size_t)pgrp * P * NPIX + tb.x;
    float* op = out + (size_t)pgrp * P * NPIX + pix;

#pragma unroll
    for (int p = 0; p < P; ++p) {
        const float* im = p0 + (size_t)p * NPIX;
        const float2 a = load_f2(im);        // row by:   (bx, bx+1)
        const float2 b = load_f2(im + N);    // row by+1: (bx, bx+1)
        const float val = w00 * a.x + w01 * a.y + w10 * b.x + w11 * b.y;
        __builtin_nontemporal_store(val, op + (size_t)p * NPIX);
    }
}

extern "C" void kernel_launch(void* const* d_in, const int* in_sizes, int n_in,
                              void* d_out, int out_size, void* d_ws, size_t ws_size,
                              hipStream_t stream) {
    const float* x  = (const float*)d_in[0];   // [128,3,224,224]
    const float* Fx = (const float*)d_in[1];   // [32,32]
    const float* Fy = (const float*)d_in[2];   // [32,32]
    float* out = (float*)d_out;

    int4* tab = (int4*)d_ws;                   // 50176 * 16 B = 803 KB

    field_kernel<<<N, 256, 0, stream>>>(Fx, Fy, tab);
    remap_kernel<<<NCHUNK * NPGRP, 256, 0, stream>>>(x, tab, out);
}

// Round 5
// 63.703 us; speedup vs baseline: 2.4661x; 2.0179x over previous
//
#include <hip/hip_runtime.h>
#include <hip/hip_fp16.h>

#define N 224        // image size
#define M 32         // CUT (number of sine modes)
#define NPIX (N * N) // 50176
#define NPLANE 384   // 128 * 3
#define PIXT 64      // pixels per remap tile
#define PLT 128      // planes per remap tile
#define NCHUNK (NPIX / PIXT)   // 784
#define NPGRP (NPLANE / PLT)   // 3
#define NXCD 8
#define CPX (NCHUNK / NXCD)    // 98
#define PI_F 3.14159265358979323846f

// ---------------- Stage 1: displacement field -> bilinear table ------------
// tab[pix] = (base = by*N+bx, fx, fy, 0), canonical form (identical to the
// reference's floor/ceil form in all cases incl. integer and clamped coords).
__global__ __launch_bounds__(256) void field_kernel(
    const float* __restrict__ Fx, const float* __restrict__ Fy,
    int4* __restrict__ tab)
{
    __shared__ float cx[M][M];
    __shared__ float cy[M][M];
    __shared__ float sy[M];

    const int t = threadIdx.x;
    const int y = blockIdx.x;

    for (int idx = t; idx < M * M; idx += 256) {
        const int i = idx / M, j = idx % M;
        const float fi = (float)(i + 1), fj = (float)(j + 1);
        const float r = sqrtf(fi * fi + fj * fj);
        const float e = (r < (float)M + 0.5f) ? (1.0f / r) : 0.0f;
        cx[i][j] = Fx[idx] * e;
        cy[i][j] = Fy[idx] * e;
    }
    if (t < M) {
        const float ys = (float)y / (float)(N - 1);
        sy[t] = sinf(PI_F * ys * (float)(t + 1));
    }
    __syncthreads();

    if (t >= N) return;
    const int x = t;

    float sx[M];
    const float xsv = (float)x / (float)(N - 1);
#pragma unroll
    for (int i = 0; i < M; ++i)
        sx[i] = sinf(PI_F * xsv * (float)(i + 1));

    float u = 0.0f, v = 0.0f;
#pragma unroll 1
    for (int j = 0; j < M; ++j) {
        float tx = 0.0f, ty = 0.0f;
#pragma unroll
        for (int i = 0; i < M; ++i) {
            tx = fmaf(cx[i][j], sx[i], tx);
            ty = fmaf(cy[i][j], sx[i], ty);
        }
        const float syj = sy[j];
        u = fmaf(syj, tx, u);
        v = fmaf(syj, ty, v);
    }

    const float dxv = 22.4f * u;   // sqrt(T)*n = 0.1*224
    const float dyv = 22.4f * v;
    const float xn = fminf(fmaxf((float)x + dxv, 0.0f), (float)(N - 1));
    const float yn = fminf(fmaxf((float)y + dyv, 0.0f), (float)(N - 1));
    const int bx = min((int)floorf(xn), N - 2);
    const int by = min((int)floorf(yn), N - 2);
    const float fx = xn - (float)bx;
    const float fy = yn - (float)by;

    tab[y * N + x] = make_int4(by * N + bx,
                               __float_as_int(fx), __float_as_int(fy), 0);
}

// ------------- Stage 2: transpose x[384][50176] f32 -> xt[50176][384] fp16 -
// 64x64 tiles via LDS; both global sides fully coalesced.
__global__ __launch_bounds__(256) void transpose_kernel(
    const float* __restrict__ x, __half* __restrict__ xt)
{
    __shared__ float t[64][65];
    const int w = threadIdx.x >> 6, l = threadIdx.x & 63;
    const int ptile = blockIdx.x % (NPLANE / 64);  // 6 plane tiles
    const int ctile = blockIdx.x / (NPLANE / 64);  // 784 pixel tiles
    const int p0 = ptile * 64, pix0 = ctile * 64;

#pragma unroll
    for (int r = 0; r < 16; ++r) {
        const int p = w * 16 + r;
        t[p][l] = x[(size_t)(p0 + p) * NPIX + pix0 + l];
    }
    __syncthreads();
#pragma unroll
    for (int r = 0; r < 16; ++r) {
        const int c = w * 16 + r;
        xt[(size_t)(pix0 + c) * NPLANE + p0 + l] = __float2half(t[l][c]);
    }
}

// ------------- Stage 3: remap with planes-in-lanes (all VMEM coalesced) ----
// Block = 64 pixels x 128 planes. Gather: per pixel, 4 coalesced half2 loads
// (lane = plane pair). LDS tile re-transposes so stores to out[plane][pix]
// are coalesced. Grid XCD-clustered: xcd owns pixel chunks [xcd*98,(xcd+1)*98).
__global__ __launch_bounds__(256) void remap_kernel(
    const __half* __restrict__ xt, const int4* __restrict__ tab,
    float* __restrict__ out)
{
    __shared__ float tile[PIXT][PLT + 2];  // [64][130] f32, rows 8B-aligned
    __shared__ int4 ltab[PIXT];

    const int tid = threadIdx.x;
    const int w = tid >> 6, l = tid & 63;

    const int bid   = blockIdx.x;
    const int xcd   = bid & 7;
    const int local = bid >> 3;          // 0..293
    const int pg    = local / CPX;       // 0..2
    const int cidx  = local % CPX;
    const int chunk = xcd * CPX + cidx;
    const int pix0  = chunk * PIXT;
    const int plane0 = pg * PLT;

    if (tid < PIXT) ltab[tid] = tab[pix0 + tid];
    __syncthreads();

#pragma unroll 8
    for (int i = 0; i < 16; ++i) {
        const int pl = w * 16 + i;       // pixel-local index
        const int4 tb = ltab[pl];
        const float fx = __int_as_float(tb.y);
        const float fy = __int_as_float(tb.z);
        const float omx = 1.0f - fx, omy = 1.0f - fy;
        const float w00 = omy * omx, w01 = omy * fx;
        const float w10 = fy * omx,  w11 = fy * fx;

        const __half2* r0 = (const __half2*)(xt + (size_t)tb.x * NPLANE + plane0);
        const __half2* r1 = (const __half2*)(xt + (size_t)(tb.x + N) * NPLANE + plane0);
        const float2 c00 = __half22float2(r0[l]);                 // (by,   bx)
        const float2 c01 = __half22float2(r0[l + NPLANE / 2]);    // (by,   bx+1)
        const float2 c10 = __half22float2(r1[l]);                 // (by+1, bx)
        const float2 c11 = __half22float2(r1[l + NPLANE / 2]);    // (by+1, bx+1)

        float2 o;
        o.x = w00 * c00.x + w01 * c01.x + w10 * c10.x + w11 * c11.x;
        o.y = w00 * c00.y + w01 * c01.y + w10 * c10.y + w11 * c11.y;
        *(float2*)&tile[pl][2 * l] = o;  // planes (2l, 2l+1) of pixel pl
    }
    __syncthreads();

    float* ob = out + (size_t)plane0 * NPIX + pix0 + l;
#pragma unroll
    for (int j2 = 0; j2 < 32; ++j2) {
        const int j = w * 32 + j2;
        ob[(size_t)j * NPIX] = tile[l][j];
    }
}

// ------------- Fallback (round-4 path) if workspace too small --------------
__device__ __forceinline__ float2 load_f2(const float* p) {
    float2 r;
    __builtin_memcpy(&r, p, sizeof(float2));
    return r;
}

#define FP 8
#define FNPGRP (NPLANE / FP)
__global__ __launch_bounds__(256) void remap_fallback(
    const float* __restrict__ x, const int4* __restrict__ tab,
    float* __restrict__ out)
{
    const int bid   = blockIdx.x;
    const int xcd   = bid % NXCD;
    const int local = bid / NXCD;
    const int pgrp  = xcd + NXCD * (local / 196);
    const int chunk = local % 196;
    const int pix   = chunk * 256 + threadIdx.x;

    const int4 tb = tab[pix];
    const float fx = __int_as_float(tb.y);
    const float fy = __int_as_float(tb.z);
    const float omx = 1.0f - fx, omy = 1.0f - fy;
    const float w00 = omy * omx, w01 = omy * fx;
    const float w10 = fy * omx,  w11 = fy * fx;

    const float* p0 = x + (size_t)pgrp * FP * NPIX + tb.x;
    float* op = out + (size_t)pgrp * FP * NPIX + pix;
#pragma unroll
    for (int p = 0; p < FP; ++p) {
        const float* im = p0 + (size_t)p * NPIX;
        const float2 a = load_f2(im);
        const float2 b = load_f2(im + N);
        const float val = w00 * a.x + w01 * a.y + w10 * b.x + w11 * b.y;
        __builtin_nontemporal_store(val, op + (size_t)p * NPIX);
    }
}

extern "C" void kernel_launch(void* const* d_in, const int* in_sizes, int n_in,
                              void* d_out, int out_size, void* d_ws, size_t ws_size,
                              hipStream_t stream) {
    const float* x  = (const float*)d_in[0];   // [128,3,224,224]
    const float* Fx = (const float*)d_in[1];   // [32,32]
    const float* Fy = (const float*)d_in[2];   // [32,32]
    float* out = (float*)d_out;

    int4* tab = (int4*)d_ws;                               // 802,816 B
    const size_t tab_bytes = (size_t)NPIX * sizeof(int4);
    const size_t xt_bytes  = (size_t)NPIX * NPLANE * sizeof(__half);  // 38.5 MB

    field_kernel<<<N, 256, 0, stream>>>(Fx, Fy, tab);

    if (ws_size >= tab_bytes + xt_bytes) {
        __half* xt = (__half*)((char*)d_ws + tab_bytes);
        transpose_kernel<<<NCHUNK * (NPLANE / 64), 256, 0, stream>>>(x, xt);
        remap_kernel<<<NCHUNK * NPGRP, 256, 0, stream>>>(xt, tab, out);
    } else {
        remap_fallback<<<196 * FNPGRP, 256, 0, stream>>>(x, tab, out);
    }
}